// Round 1
// baseline (121.152 us; speedup 1.0000x reference)
//
#include <hip/hip_runtime.h>

// EMD-ish loss: mean over (b,n) of min_m ||pred[b,n] - target[b,m]||
// B=32, N=M=4096, fp32. Compute-bound on fp32 VALU (no fp32 MFMA on CDNA4).
//
// Trick: per target precompute (-2tx,-2ty,-2tz,|t|^2) packed as float4 in LDS.
// Then per pair d2' = fma(px,-2tx, fma(py,-2ty, fma(pz,-2tz, t2))) = 3 FMA,
// and |p|^2 is added once after the min loop (monotonic under min).
// All lanes read the same LDS float4 per iteration -> broadcast, no conflicts.

constexpr int Bc = 32;
constexpr int Nc = 4096;
constexpr int Mc = 4096;
constexpr int BLOCK = 256;
constexpr int CHUNKS = Nc / BLOCK;  // 16 pred-chunks per batch -> 512 blocks total

__global__ __launch_bounds__(BLOCK) void emd_min_kernel(
    const float* __restrict__ pred, const float* __restrict__ target,
    float* __restrict__ out) {
  __shared__ float4 tgt[Mc];  // exactly 64 KB -> 2 blocks/CU

  const int b = blockIdx.x >> 4;       // blockIdx.x / CHUNKS
  const int chunk = blockIdx.x & 15;   // blockIdx.x % CHUNKS

  // Stage + transform targets for this batch: 256 threads x 16 targets each.
  const float* tb = target + (size_t)b * Mc * 3;
  for (int m = threadIdx.x; m < Mc; m += BLOCK) {
    float tx = tb[3 * m + 0];
    float ty = tb[3 * m + 1];
    float tz = tb[3 * m + 2];
    tgt[m] = make_float4(-2.0f * tx, -2.0f * ty, -2.0f * tz,
                         fmaf(tx, tx, fmaf(ty, ty, tz * tz)));
  }
  __syncthreads();

  // One pred point per thread.
  const int n = chunk * BLOCK + threadIdx.x;
  const float* pb = pred + ((size_t)b * Nc + n) * 3;
  const float px = pb[0], py = pb[1], pz = pb[2];
  const float p2 = fmaf(px, px, fmaf(py, py, pz * pz));

  // 4 independent min chains; fminf(fminf(r,d0),d1) should fold to v_min3_f32.
  float r0 = 3.4e38f, r1 = 3.4e38f, r2 = 3.4e38f, r3 = 3.4e38f;
#pragma unroll 2
  for (int m = 0; m < Mc; m += 8) {
    float4 t0 = tgt[m + 0];
    float4 t1 = tgt[m + 1];
    float4 t2 = tgt[m + 2];
    float4 t3 = tgt[m + 3];
    float4 t4 = tgt[m + 4];
    float4 t5 = tgt[m + 5];
    float4 t6 = tgt[m + 6];
    float4 t7 = tgt[m + 7];
    float d0 = fmaf(px, t0.x, fmaf(py, t0.y, fmaf(pz, t0.z, t0.w)));
    float d1 = fmaf(px, t1.x, fmaf(py, t1.y, fmaf(pz, t1.z, t1.w)));
    float d2 = fmaf(px, t2.x, fmaf(py, t2.y, fmaf(pz, t2.z, t2.w)));
    float d3 = fmaf(px, t3.x, fmaf(py, t3.y, fmaf(pz, t3.z, t3.w)));
    float d4 = fmaf(px, t4.x, fmaf(py, t4.y, fmaf(pz, t4.z, t4.w)));
    float d5 = fmaf(px, t5.x, fmaf(py, t5.y, fmaf(pz, t5.z, t5.w)));
    float d6 = fmaf(px, t6.x, fmaf(py, t6.y, fmaf(pz, t6.z, t6.w)));
    float d7 = fmaf(px, t7.x, fmaf(py, t7.y, fmaf(pz, t7.z, t7.w)));
    r0 = fminf(fminf(r0, d0), d1);
    r1 = fminf(fminf(r1, d2), d3);
    r2 = fminf(fminf(r2, d4), d5);
    r3 = fminf(fminf(r3, d6), d7);
  }
  float rmin = fminf(fminf(r0, r1), fminf(r2, r3));
  float dist = sqrtf(fmaxf(rmin + p2, 0.0f));

  // Block-sum of dist -> one atomicAdd per block (scaled to produce the mean).
  float s = dist;
#pragma unroll
  for (int off = 32; off > 0; off >>= 1) s += __shfl_down(s, off, 64);

  // Reuse tgt LDS for the 4 per-wave partials (all reads of tgt are done).
  __syncthreads();
  float* wsum = (float*)tgt;
  if ((threadIdx.x & 63) == 0) wsum[threadIdx.x >> 6] = s;
  __syncthreads();
  if (threadIdx.x == 0) {
    float tot = (wsum[0] + wsum[1]) + (wsum[2] + wsum[3]);
    atomicAdd(out, tot * (1.0f / (float)(Bc * Nc)));
  }
}

extern "C" void kernel_launch(void* const* d_in, const int* in_sizes, int n_in,
                              void* d_out, int out_size, void* d_ws, size_t ws_size,
                              hipStream_t stream) {
  const float* pred = (const float*)d_in[0];
  const float* target = (const float*)d_in[1];
  float* out = (float*)d_out;

  // d_out is re-poisoned (0xAA) before every replay; zero it on-stream
  // (hipMemsetAsync is graph-capture safe).
  hipMemsetAsync(out, 0, sizeof(float), stream);

  emd_min_kernel<<<dim3(Bc * CHUNKS), dim3(BLOCK), 0, stream>>>(pred, target, out);
}

// Round 2
// 108.285 us; speedup vs baseline: 1.1188x; 1.1188x over previous
//
#include <hip/hip_runtime.h>

// min_m ||pred[b,n]-target[b,m]|| mean over (b,n). B=32, N=M=4096, fp32.
// Pure fp32 VALU problem (no fp32 MFMA on CDNA4). Floor: 3 FMA + ~0.5 min
// per pair = ~24 us at 157 TF.
//
// R1 counters: VALUBusy 65%, Occupancy 19.5% (8 waves/CU), DS:VALU ~1:3.5.
// R2 design: P=4 preds/thread (DS issues /4, 4x ILP), MS=8 target splits
// (8 KB LDS, 1024 blocks -> 4 blocks/CU, 16 waves). Cross-block min combine
// via atomicMin on uint bits of clamped d2 (>=0 so float order == uint order),
// ws init 0xFF (= +inf for unsigned min). Second kernel: sqrt + mean.

constexpr int Bc = 32;
constexpr int Nc = 4096;
constexpr int Mc = 4096;
constexpr int BLOCK = 256;
constexpr int P = 4;                      // preds per thread
constexpr int MS = 8;                     // target splits per batch
constexpr int TGTS = Mc / MS;             // 512 targets staged per block
constexpr int NCH = Nc / (BLOCK * P);     // 4 pred chunks per batch
// grid A = Bc * NCH * MS = 1024 blocks

__global__ __launch_bounds__(BLOCK) void emd_partial_kernel(
    const float* __restrict__ pred, const float* __restrict__ target,
    unsigned int* __restrict__ wmin) {
  __shared__ float4 tgt[TGTS];  // 8 KB

  const int bid = blockIdx.x;
  const int b = bid >> 5;            // / (NCH*MS)
  const int chunk = (bid >> 3) & 3;  // NCH index
  const int ms = bid & 7;            // target-split index

  // Stage + transform 512 targets: (-2tx,-2ty,-2tz,|t|^2).
  const float* tb = target + ((size_t)b * Mc + ms * TGTS) * 3;
  for (int m = threadIdx.x; m < TGTS; m += BLOCK) {
    float tx = tb[3 * m + 0];
    float ty = tb[3 * m + 1];
    float tz = tb[3 * m + 2];
    tgt[m] = make_float4(-2.0f * tx, -2.0f * ty, -2.0f * tz,
                         fmaf(tx, tx, fmaf(ty, ty, tz * tz)));
  }
  __syncthreads();

  // P=4 pred points per thread, strided by 256 for coalesced loads.
  float px[P], py[P], pz[P];
  const int nbase = chunk * (BLOCK * P) + threadIdx.x;
#pragma unroll
  for (int k = 0; k < P; ++k) {
    const float* pb = pred + ((size_t)b * Nc + nbase + k * BLOCK) * 3;
    px[k] = pb[0]; py[k] = pb[1]; pz[k] = pb[2];
  }

  // Two independent min chains per pred; fminf(fminf(a,b),r) folds to min3.
  float r0[P], r1[P];
#pragma unroll
  for (int k = 0; k < P; ++k) { r0[k] = 3.4e38f; r1[k] = 3.4e38f; }

  for (int m = 0; m < TGTS; m += 4) {
    float4 ta = tgt[m + 0];
    float4 tb4 = tgt[m + 1];
    float4 tc = tgt[m + 2];
    float4 td = tgt[m + 3];
#pragma unroll
    for (int k = 0; k < P; ++k) {
      float da = fmaf(px[k], ta.x, fmaf(py[k], ta.y, fmaf(pz[k], ta.z, ta.w)));
      float db = fmaf(px[k], tb4.x, fmaf(py[k], tb4.y, fmaf(pz[k], tb4.z, tb4.w)));
      float dc = fmaf(px[k], tc.x, fmaf(py[k], tc.y, fmaf(pz[k], tc.z, tc.w)));
      float dd = fmaf(px[k], td.x, fmaf(py[k], td.y, fmaf(pz[k], td.z, td.w)));
      r0[k] = fminf(fminf(da, db), r0[k]);  // v_min3_f32
      r1[k] = fminf(fminf(dc, dd), r1[k]);
    }
  }

#pragma unroll
  for (int k = 0; k < P; ++k) {
    const float* pb = pred + ((size_t)b * Nc + nbase + k * BLOCK) * 3;
    float p2 = fmaf(px[k], px[k], fmaf(py[k], py[k], pz[k] * pz[k]));
    float d2 = fmaxf(fminf(r0[k], r1[k]) + p2, 0.0f);
    int n = nbase + k * BLOCK;
    atomicMin(&wmin[b * Nc + n], __float_as_uint(d2));
    (void)pb;
  }
}

__global__ __launch_bounds__(BLOCK) void emd_finish_kernel(
    const unsigned int* __restrict__ wmin, float* __restrict__ out) {
  __shared__ float wsum[4];
  const int i = blockIdx.x * BLOCK + threadIdx.x;
  float d = sqrtf(__uint_as_float(wmin[i]));

  float s = d;
#pragma unroll
  for (int off = 32; off > 0; off >>= 1) s += __shfl_down(s, off, 64);
  if ((threadIdx.x & 63) == 0) wsum[threadIdx.x >> 6] = s;
  __syncthreads();
  if (threadIdx.x == 0) {
    float tot = (wsum[0] + wsum[1]) + (wsum[2] + wsum[3]);
    atomicAdd(out, tot * (1.0f / (float)(Bc * Nc)));
  }
}

extern "C" void kernel_launch(void* const* d_in, const int* in_sizes, int n_in,
                              void* d_out, int out_size, void* d_ws, size_t ws_size,
                              hipStream_t stream) {
  const float* pred = (const float*)d_in[0];
  const float* target = (const float*)d_in[1];
  float* out = (float*)d_out;
  unsigned int* wmin = (unsigned int*)d_ws;  // Bc*Nc uints = 512 KB

  // 0xFFFFFFFF acts as +inf for unsigned atomicMin; out accumulated via atomicAdd.
  hipMemsetAsync(wmin, 0xFF, (size_t)Bc * Nc * sizeof(unsigned int), stream);
  hipMemsetAsync(out, 0, sizeof(float), stream);

  emd_partial_kernel<<<dim3(Bc * NCH * MS), dim3(BLOCK), 0, stream>>>(pred, target, wmin);
  emd_finish_kernel<<<dim3(Bc * Nc / BLOCK), dim3(BLOCK), 0, stream>>>(wmin, out);
}